// Round 10
// baseline (235.931 us; speedup 1.0000x reference)
//
#include <hip/hip_runtime.h>
#include <hip/hip_bf16.h>
#include <stdint.h>

typedef __hip_bfloat16 bf16;
typedef __attribute__((ext_vector_type(8))) short short8;   // 8 bf16 = 4 VGPRs (MFMA A/B frag)
typedef __attribute__((ext_vector_type(4))) float floatx4;  // 16x16 MFMA C/D frag

#define AS1(p) ((const __attribute__((address_space(1))) void*)(p))
#define AS3(p) ((__attribute__((address_space(3))) void*)(p))

#define M_DIM 4096
#define H_DIM 1024
#define STAGE 24576          // A 8KB + B 16KB per K-step(32); 3 stages = 72KB -> 2 blocks/CU

// fp32 -> bf16 bits, round-to-nearest-even (inputs are finite)
__device__ __forceinline__ unsigned short f2bf(float f) {
    uint32_t u = __float_as_uint(f);
    uint32_t r = (u + 0x7FFFu + ((u >> 16) & 1u)) >> 16;
    return (unsigned short)r;
}
__device__ __forceinline__ float fast_sigmoid(float v) {
    return 1.0f / (1.0f + __expf(-v));
}
__device__ __forceinline__ float fast_tanh(float v) {
    return 2.0f / (1.0f + __expf(-2.0f * v)) - 1.0f;
}

// ---------------------------------------------------------------------------
// Kernel 1: PACK fp32 -> bf16 1KB chunks in 16x16x32-fragment lane order:
// chunk = [4 kg][16 row][8 bf16]; lane l holds bytes l*16 (row=l&15, kg=l>>4).
// Unified KT in [0,64): KT<32 -> x / Wx (k = KT*32..), KT>=32 -> h / Wh.
// Chunk map (32768 x 1KB = 32MB):
//   A (W<16384):  W = mx*512 + KT*8 + ch      (mx<32: 128-row panel, ch<8:
//                 16-row group); row = mx*128 + ch*16 + (l&15)
//   B (W>=16384): W-16384 = ny*1024 + KT*16 + b   (ny<16: 64-col panel,
//                 b = g*4 + c4: gate g, 16-col group c4);
//                 row = ny*64 + c4*16 + (l&15)
// (This pack + chunk map is absmax-validated by rounds 7/8/9.)
__global__ __launch_bounds__(256)
void pack_bf16(const float* __restrict__ x, const float* __restrict__ h,
               const float* Wxf, const float* Wxi, const float* Wxo, const float* Wxc,
               const float* Whf, const float* Whi, const float* Who, const float* Whc,
               unsigned short* __restrict__ ws)
{
    const int w = threadIdx.x >> 6;
    const int l = threadIdx.x & 63;
    const uint32_t W = blockIdx.x * 4u + (uint32_t)w;   // chunk id [0, 32768)

    const uint32_t kg = (uint32_t)l >> 4;    // k-group of 8
    const uint32_t rr = (uint32_t)l & 15u;   // row/col within fragment

    const float* src;
    uint32_t row, ktl;
    if (W < 16384u) {                    // A-chunks (x / h)
        const uint32_t ch = W & 7u;
        const uint32_t KT = (W >> 3) & 63u;
        const uint32_t mx = W >> 9;
        src = (KT < 32u) ? x : h;
        ktl = KT & 31u;
        row = mx * 128u + ch * 16u + rr;
    } else {                             // B-chunks (Wx_g / Wh_g)
        const uint32_t V  = W - 16384u;
        const uint32_t b  = V & 15u;
        const uint32_t KT = (V >> 4) & 63u;
        const uint32_t ny = V >> 10;
        const uint32_t g  = b >> 2;
        const uint32_t c4 = b & 3u;
        if (KT < 32u)
            src = (g == 0) ? Wxf : (g == 1) ? Wxi : (g == 2) ? Wxo : Wxc;
        else
            src = (g == 0) ? Whf : (g == 1) ? Whi : (g == 2) ? Who : Whc;
        ktl = KT & 31u;
        row = ny * 64u + c4 * 16u + rr;
    }
    const float* s = src + (size_t)row * 1024u + ktl * 32u + kg * 8u;
    const float4 v0 = *(const float4*)s;
    const float4 v1 = *(const float4*)(s + 4);
    short8 pk;
    pk[0] = (short)f2bf(v0.x); pk[1] = (short)f2bf(v0.y);
    pk[2] = (short)f2bf(v0.z); pk[3] = (short)f2bf(v0.w);
    pk[4] = (short)f2bf(v1.x); pk[5] = (short)f2bf(v1.y);
    pk[6] = (short)f2bf(v1.z); pk[7] = (short)f2bf(v1.w);
    *(short8*)(ws + (size_t)W * 512u + (uint32_t)l * 8u) = pk;
}

// ---------------------------------------------------------------------------
// Kernel 2: fused 4-gate GEMM + LSTM pointwise.  Round-9 structure (the
// acc=64 traffic optimum) with two schedule changes:
//  - sched_barrier(0) REMOVED from the per-iter barrier.  Correctness is
//    carried by lgkmcnt(0) alone (ds_reads are memory ops: pinned by the
//    "memory" clobber and drained before s_barrier -> the stage-ring WAR is
//    closed).  MFMAs (register-only) may now sink across the barrier into
//    the next iteration's issue bubble -- cross-iteration pipelining.
//  - epilogue c/bias reads prefetched under the last two K-steps with
//    hand-counted tail waits: 24 prefetch loads after ITER(61) ->
//    outstanding = 3(loads62)+3(loads63)+24; vmcnt(27) retires loads(62),
//    vmcnt(24) retires loads(63); prefetch data lands during tail COMPUTEs.
#define GLL(srcp, dstp) __builtin_amdgcn_global_load_lds(AS1(srcp), AS3(dstp), 16, 0, 0)
#define WAITB(N) \
    asm volatile("s_waitcnt vmcnt(" #N ") lgkmcnt(0)\ns_barrier" ::: "memory")

#define MFMA16(a, b, c) __builtin_amdgcn_mfma_f32_16x16x32_bf16((a), (b), (c), 0, 0, 0)

#define ISSUE(SL) do {                                                        \
    GLL(p0, lds + (SL)*STAGE + lo0); p0 += ks0;                               \
    GLL(p1, lds + (SL)*STAGE + lo1); p1 += ks1;                               \
    GLL(p2, lds + (SL)*STAGE + lo2); p2 += ks2;                               \
} while (0)

#define COMPUTE(SC) do {                                                      \
    const short8 a0_ = *(const short8*)(ldsA + (SC)*STAGE + 0);               \
    const short8 a1_ = *(const short8*)(ldsA + (SC)*STAGE + 1024);            \
    const short8 a2_ = *(const short8*)(ldsA + (SC)*STAGE + 2048);            \
    const short8 a3_ = *(const short8*)(ldsA + (SC)*STAGE + 3072);            \
    _Pragma("unroll")                                                         \
    for (int g = 0; g < 4; ++g) {                                             \
        const short8 bf_ = *(const short8*)(ldsB + (SC)*STAGE + g * 4096);    \
        acc[g][0] = MFMA16(a0_, bf_, acc[g][0]);                              \
        acc[g][1] = MFMA16(a1_, bf_, acc[g][1]);                              \
        acc[g][2] = MFMA16(a2_, bf_, acc[g][2]);                              \
        acc[g][3] = MFMA16(a3_, bf_, acc[g][3]);                              \
    }                                                                         \
} while (0)

#define ITER(SC, SL) do { WAITB(3); ISSUE(SL); COMPUTE(SC); } while (0)

__global__ __launch_bounds__(512, 4)
void lstm_fused_kernel(const unsigned short* __restrict__ ws,
                       const float* __restrict__ c,
                       const float* __restrict__ bxf, const float* __restrict__ bhf,
                       const float* __restrict__ bxi, const float* __restrict__ bhi,
                       const float* __restrict__ bxo, const float* __restrict__ bho,
                       const float* __restrict__ bxc, const float* __restrict__ bhc,
                       float* __restrict__ out)
{
    __shared__ __align__(16) char lds[3 * STAGE];   // 72 KB

    const int tid  = threadIdx.x;
    const int w    = tid >> 6;     // 0..7
    const int lane = tid & 63;

    // XCD-aware block swizzle: grid 512 = 32 mx x 16 ny
    const int bid = blockIdx.x;
    const int mx  = bid >> 4;                              // [0,32)
    const int ny  = ((bid & 7) << 1) | ((bid >> 3) & 1);   // [0,16)
    const int bm0 = mx * 128;
    const int bn0 = ny * 64;

    const int wM  = w & 1;         // 64-row half
    const int wcg = w >> 1;        // 16-col group within each gate [0,4)

    // epilogue coordinates (hoisted; used by the tail prefetch too)
    const int lrc   = lane & 15;
    const int lquad = lane >> 4;
    const int colg  = bn0 + wcg * 16 + lrc;
    const int wrow  = wM * 64;

    // staging: 24 chunks/stage; wave w DMAs ch = w*3 + i, i<3.
    // ch<8: A chunk ch; ch>=8: B chunk b = ch-8 (= g*4+c4).
    // LDS stage layout: loff = ch*1024 uniformly (A [0,8K), B 8K + b*1024).
    const unsigned short* p0; const unsigned short* p1; const unsigned short* p2;
    uint32_t lo0, lo1, lo2, ks0, ks1, ks2;
#define CHDEC(CH, P, LO, KS) do {                                             \
    const uint32_t ch_ = (uint32_t)(CH);                                      \
    if (ch_ < 8u) {                                                           \
        P  = ws + ((uint32_t)mx * 512u + ch_) * 512u + (uint32_t)lane * 8u;   \
        KS = 8u * 512u;                                                       \
    } else {                                                                  \
        const uint32_t b_ = ch_ - 8u;                                         \
        P  = ws + (16384u + (uint32_t)ny * 1024u + b_) * 512u                 \
                + (uint32_t)lane * 8u;                                        \
        KS = 16u * 512u;                                                      \
    }                                                                         \
    LO = ch_ * 1024u;                                                         \
} while (0)
    CHDEC(w * 3 + 0, p0, lo0, ks0);
    CHDEC(w * 3 + 1, p1, lo1, ks1);
    CHDEC(w * 3 + 2, p2, lo2, ks2);
#undef CHDEC

    // fragment base pointers; all LDS reads are base + immediate offset.
    // A frags: chunk wM*4 + mt.  B frags: chunk b = g*4 + wcg.
    const char* ldsA = lds + (uint32_t)lane * 16u + (uint32_t)wM * 4096u;
    const char* ldsB = lds + (uint32_t)lane * 16u + 8192u + (uint32_t)wcg * 1024u;

    floatx4 acc[4][4];   // [gate][m-tile] = 64 fp32/lane (proven spill-free)
#pragma unroll
    for (int g = 0; g < 4; ++g)
#pragma unroll
        for (int mt = 0; mt < 4; ++mt)
            acc[g][mt] = (floatx4){0.f, 0.f, 0.f, 0.f};

    // prologue: stages 0,1 in flight (6 outstanding/wave)
    ISSUE(0);
    ISSUE(1);

    // 64 K-steps; ITER(kt) computes stage kt%3, issues kt+2 -> (kt+2)%3.
    for (int t = 0; t < 20; ++t) {
        ITER(0, 2); ITER(1, 0); ITER(2, 1);     // kt = 3t, 3t+1, 3t+2
    }
    ITER(0, 2);                                 // kt = 60
    ITER(1, 0);                                 // kt = 61 (issues loads(63))

    // --- tail: prefetch epilogue operands under the last two COMPUTEs ---
    // 16 c-values (scattered, stride 4096B) + 8 bias scalars.
    float cv[4][4];
#pragma unroll
    for (int mt = 0; mt < 4; ++mt)
#pragma unroll
        for (int r = 0; r < 4; ++r)
            cv[mt][r] = c[(size_t)(bm0 + wrow + mt * 16 + lquad * 4 + r) * H_DIM + colg];
    const float bxf_v = bxf[colg]; const float bhf_v = bhf[colg];
    const float bxi_v = bxi[colg]; const float bhi_v = bhi[colg];
    const float bxo_v = bxo[colg]; const float bho_v = bho[colg];
    const float bxc_v = bxc[colg]; const float bhc_v = bhc[colg];
    // outstanding now: 3(loads62) + 3(loads63) + 24(prefetch) = 30
    WAITB(27); COMPUTE(2);                      // kt = 62 (loads62 retired)
    WAITB(24); COMPUTE(0);                      // kt = 63 (loads63 retired)

    // ------------------------------------------------------------------ epi
    // All 4 gates wave-local.  C/D: col = lane&15, row = (lane>>4)*4 + reg
    float* out_ct = out;
    float* out_ht = out + (size_t)M_DIM * H_DIM;

    const float bf_ = bxf_v + bhf_v;
    const float bi_ = bxi_v + bhi_v;
    const float bo_ = bxo_v + bho_v;
    const float bc_ = bxc_v + bhc_v;

#pragma unroll
    for (int mt = 0; mt < 4; ++mt) {
#pragma unroll
        for (int r = 0; r < 4; ++r) {
            const int row = bm0 + wrow + mt * 16 + lquad * 4 + r;
            const float f    = fast_sigmoid(acc[0][mt][r] + bf_);
            const float ii   = fast_sigmoid(acc[1][mt][r] + bi_);
            const float o    = fast_sigmoid(acc[2][mt][r] + bo_);
            const float ctil = fast_tanh(acc[3][mt][r] + bc_);
            const float ctn  = f * cv[mt][r] + ctil * ii;
            const float htn  = fast_tanh(ctn) * o;
            out_ct[(size_t)row * H_DIM + colg] = ctn;
            out_ht[(size_t)row * H_DIM + colg] = htn;
        }
    }
}

extern "C" void kernel_launch(void* const* d_in, const int* in_sizes, int n_in,
                              void* d_out, int out_size, void* d_ws, size_t ws_size,
                              hipStream_t stream) {
    (void)in_sizes; (void)n_in; (void)out_size; (void)ws_size;
    const float* x   = (const float*)d_in[0];
    const float* c   = (const float*)d_in[1];
    const float* h   = (const float*)d_in[2];
    const float* Wxf = (const float*)d_in[3];  const float* bxf = (const float*)d_in[4];
    const float* Whf = (const float*)d_in[5];  const float* bhf = (const float*)d_in[6];
    const float* Wxi = (const float*)d_in[7];  const float* bxi = (const float*)d_in[8];
    const float* Whi = (const float*)d_in[9];  const float* bhi = (const float*)d_in[10];
    const float* Wxo = (const float*)d_in[11]; const float* bxo = (const float*)d_in[12];
    const float* Who = (const float*)d_in[13]; const float* bho = (const float*)d_in[14];
    const float* Wxc = (const float*)d_in[15]; const float* bxc = (const float*)d_in[16];
    const float* Whc = (const float*)d_in[17]; const float* bhc = (const float*)d_in[18];
    float* out = (float*)d_out;
    unsigned short* ws = (unsigned short*)d_ws;   // 32768 chunks x 1 KB = 32 MB

    pack_bf16<<<8192, 256, 0, stream>>>(x, h,
        Wxf, Wxi, Wxo, Wxc, Whf, Whi, Who, Whc, ws);

    lstm_fused_kernel<<<512, 512, 0, stream>>>(ws, c,
        bxf, bhf, bxi, bhi, bxo, bho, bxc, bhc, out);
}

// Round 11
// 223.057 us; speedup vs baseline: 1.0577x; 1.0577x over previous
//
#include <hip/hip_runtime.h>
#include <hip/hip_bf16.h>
#include <stdint.h>

typedef __hip_bfloat16 bf16;
typedef __attribute__((ext_vector_type(8))) short short8;   // 8 bf16 = 4 VGPRs (MFMA A/B frag)
typedef __attribute__((ext_vector_type(4))) float floatx4;  // 16x16 MFMA C/D frag

#define AS1(p) ((const __attribute__((address_space(1))) void*)(p))
#define AS3(p) ((__attribute__((address_space(3))) void*)(p))

#define M_DIM 4096
#define H_DIM 1024
#define STAGE 24576          // A 8KB + B 16KB per K-step(32); 3 stages = 72KB -> 2 blocks/CU

// fp32 -> bf16 bits, round-to-nearest-even (inputs are finite)
__device__ __forceinline__ unsigned short f2bf(float f) {
    uint32_t u = __float_as_uint(f);
    uint32_t r = (u + 0x7FFFu + ((u >> 16) & 1u)) >> 16;
    return (unsigned short)r;
}
__device__ __forceinline__ float fast_sigmoid(float v) {
    return 1.0f / (1.0f + __expf(-v));
}
__device__ __forceinline__ float fast_tanh(float v) {
    return 2.0f / (1.0f + __expf(-2.0f * v)) - 1.0f;
}

// ---------------------------------------------------------------------------
// Kernel 1: PACK fp32 -> bf16 1KB chunks in 16x16x32-fragment lane order:
// chunk = [4 kg][16 row][8 bf16]; lane l holds bytes l*16 (row=l&15, kg=l>>4).
// Unified KT in [0,64): KT<32 -> x / Wx (k = KT*32..), KT>=32 -> h / Wh.
// Chunk map (32768 x 1KB = 32MB):
//   A (W<16384):  W = mx*512 + KT*8 + ch      (mx<32: 128-row panel, ch<8:
//                 16-row group); row = mx*128 + ch*16 + (l&15)
//   B (W>=16384): W-16384 = ny*1024 + KT*16 + b   (ny<16: 64-col panel,
//                 b = g*4 + c4: gate g, 16-col group c4);
//                 row = ny*64 + c4*16 + (l&15)
// (This pack + chunk map is absmax-validated by rounds 7-10.)
__global__ __launch_bounds__(256)
void pack_bf16(const float* __restrict__ x, const float* __restrict__ h,
               const float* Wxf, const float* Wxi, const float* Wxo, const float* Wxc,
               const float* Whf, const float* Whi, const float* Who, const float* Whc,
               unsigned short* __restrict__ ws)
{
    const int w = threadIdx.x >> 6;
    const int l = threadIdx.x & 63;
    const uint32_t W = blockIdx.x * 4u + (uint32_t)w;   // chunk id [0, 32768)

    const uint32_t kg = (uint32_t)l >> 4;    // k-group of 8
    const uint32_t rr = (uint32_t)l & 15u;   // row/col within fragment

    const float* src;
    uint32_t row, ktl;
    if (W < 16384u) {                    // A-chunks (x / h)
        const uint32_t ch = W & 7u;
        const uint32_t KT = (W >> 3) & 63u;
        const uint32_t mx = W >> 9;
        src = (KT < 32u) ? x : h;
        ktl = KT & 31u;
        row = mx * 128u + ch * 16u + rr;
    } else {                             // B-chunks (Wx_g / Wh_g)
        const uint32_t V  = W - 16384u;
        const uint32_t b  = V & 15u;
        const uint32_t KT = (V >> 4) & 63u;
        const uint32_t ny = V >> 10;
        const uint32_t g  = b >> 2;
        const uint32_t c4 = b & 3u;
        if (KT < 32u)
            src = (g == 0) ? Wxf : (g == 1) ? Wxi : (g == 2) ? Wxo : Wxc;
        else
            src = (g == 0) ? Whf : (g == 1) ? Whi : (g == 2) ? Who : Whc;
        ktl = KT & 31u;
        row = ny * 64u + c4 * 16u + rr;
    }
    const float* s = src + (size_t)row * 1024u + ktl * 32u + kg * 8u;
    const float4 v0 = *(const float4*)s;
    const float4 v1 = *(const float4*)(s + 4);
    short8 pk;
    pk[0] = (short)f2bf(v0.x); pk[1] = (short)f2bf(v0.y);
    pk[2] = (short)f2bf(v0.z); pk[3] = (short)f2bf(v0.w);
    pk[4] = (short)f2bf(v1.x); pk[5] = (short)f2bf(v1.y);
    pk[6] = (short)f2bf(v1.z); pk[7] = (short)f2bf(v1.w);
    *(short8*)(ws + (size_t)W * 512u + (uint32_t)l * 8u) = pk;
}

// ---------------------------------------------------------------------------
// Kernel 2: fused 4-gate GEMM + LSTM pointwise.  EXACT round-9 structure
// (acc=64 traffic optimum; 69.7 us, WRITE 32.8 MB, VGPR 64) with ONE change:
//  - sched_barrier(0) removed from the per-iter barrier.  Correctness is
//    carried by lgkmcnt(0) alone: ds_reads are memory ops (pinned by the
//    "memory" clobber, drained before s_barrier -> stage-ring WAR closed);
//    register-only MFMAs may sink across the barrier into the next
//    iteration's issue bubble = cross-iteration pipelining.
//    (HW-validated for correctness by round-10's passing absmax/tripwire.)
//  - round-10's epilogue prefetch REVERTED (it spilled: +44 MB scratch).
#define GLL(srcp, dstp) __builtin_amdgcn_global_load_lds(AS1(srcp), AS3(dstp), 16, 0, 0)
#define WAITB(N) \
    asm volatile("s_waitcnt vmcnt(" #N ") lgkmcnt(0)\ns_barrier" ::: "memory")

#define MFMA16(a, b, c) __builtin_amdgcn_mfma_f32_16x16x32_bf16((a), (b), (c), 0, 0, 0)

#define ISSUE(SL) do {                                                        \
    GLL(p0, lds + (SL)*STAGE + lo0); p0 += ks0;                               \
    GLL(p1, lds + (SL)*STAGE + lo1); p1 += ks1;                               \
    GLL(p2, lds + (SL)*STAGE + lo2); p2 += ks2;                               \
} while (0)

#define COMPUTE(SC) do {                                                      \
    const short8 a0_ = *(const short8*)(ldsA + (SC)*STAGE + 0);               \
    const short8 a1_ = *(const short8*)(ldsA + (SC)*STAGE + 1024);            \
    const short8 a2_ = *(const short8*)(ldsA + (SC)*STAGE + 2048);            \
    const short8 a3_ = *(const short8*)(ldsA + (SC)*STAGE + 3072);            \
    _Pragma("unroll")                                                         \
    for (int g = 0; g < 4; ++g) {                                             \
        const short8 bf_ = *(const short8*)(ldsB + (SC)*STAGE + g * 4096);    \
        acc[g][0] = MFMA16(a0_, bf_, acc[g][0]);                              \
        acc[g][1] = MFMA16(a1_, bf_, acc[g][1]);                              \
        acc[g][2] = MFMA16(a2_, bf_, acc[g][2]);                              \
        acc[g][3] = MFMA16(a3_, bf_, acc[g][3]);                              \
    }                                                                         \
} while (0)

#define ITER(SC, SL) do { WAITB(3); ISSUE(SL); COMPUTE(SC); } while (0)

__global__ __launch_bounds__(512, 4)
void lstm_fused_kernel(const unsigned short* __restrict__ ws,
                       const float* __restrict__ c,
                       const float* __restrict__ bxf, const float* __restrict__ bhf,
                       const float* __restrict__ bxi, const float* __restrict__ bhi,
                       const float* __restrict__ bxo, const float* __restrict__ bho,
                       const float* __restrict__ bxc, const float* __restrict__ bhc,
                       float* __restrict__ out)
{
    __shared__ __align__(16) char lds[3 * STAGE];   // 72 KB

    const int tid  = threadIdx.x;
    const int w    = tid >> 6;     // 0..7
    const int lane = tid & 63;

    // XCD-aware block swizzle: grid 512 = 32 mx x 16 ny
    const int bid = blockIdx.x;
    const int mx  = bid >> 4;                              // [0,32)
    const int ny  = ((bid & 7) << 1) | ((bid >> 3) & 1);   // [0,16)
    const int bm0 = mx * 128;
    const int bn0 = ny * 64;

    const int wM  = w & 1;         // 64-row half
    const int wcg = w >> 1;        // 16-col group within each gate [0,4)

    // staging: 24 chunks/stage; wave w DMAs ch = w*3 + i, i<3.
    // ch<8: A chunk ch; ch>=8: B chunk b = ch-8 (= g*4+c4).
    // LDS stage layout: loff = ch*1024 uniformly (A [0,8K), B 8K + b*1024).
    const unsigned short* p0; const unsigned short* p1; const unsigned short* p2;
    uint32_t lo0, lo1, lo2, ks0, ks1, ks2;
#define CHDEC(CH, P, LO, KS) do {                                             \
    const uint32_t ch_ = (uint32_t)(CH);                                      \
    if (ch_ < 8u) {                                                           \
        P  = ws + ((uint32_t)mx * 512u + ch_) * 512u + (uint32_t)lane * 8u;   \
        KS = 8u * 512u;                                                       \
    } else {                                                                  \
        const uint32_t b_ = ch_ - 8u;                                         \
        P  = ws + (16384u + (uint32_t)ny * 1024u + b_) * 512u                 \
                + (uint32_t)lane * 8u;                                        \
        KS = 16u * 512u;                                                      \
    }                                                                         \
    LO = ch_ * 1024u;                                                         \
} while (0)
    CHDEC(w * 3 + 0, p0, lo0, ks0);
    CHDEC(w * 3 + 1, p1, lo1, ks1);
    CHDEC(w * 3 + 2, p2, lo2, ks2);
#undef CHDEC

    // fragment base pointers; all LDS reads are base + immediate offset.
    // A frags: chunk wM*4 + mt.  B frags: chunk b = g*4 + wcg.
    const char* ldsA = lds + (uint32_t)lane * 16u + (uint32_t)wM * 4096u;
    const char* ldsB = lds + (uint32_t)lane * 16u + 8192u + (uint32_t)wcg * 1024u;

    floatx4 acc[4][4];   // [gate][m-tile] = 64 fp32/lane (proven spill-free)
#pragma unroll
    for (int g = 0; g < 4; ++g)
#pragma unroll
        for (int mt = 0; mt < 4; ++mt)
            acc[g][mt] = (floatx4){0.f, 0.f, 0.f, 0.f};

    // prologue: stages 0,1 in flight (6 outstanding/wave)
    ISSUE(0);
    ISSUE(1);

    // 64 K-steps; ITER(kt) computes stage kt%3, issues kt+2 -> (kt+2)%3.
    for (int t = 0; t < 20; ++t) {
        ITER(0, 2); ITER(1, 0); ITER(2, 1);     // kt = 3t, 3t+1, 3t+2
    }
    ITER(0, 2);                                 // kt = 60
    ITER(1, 0);                                 // kt = 61 (issues loads(63))
    WAITB(3); COMPUTE(2);                       // kt = 62
    WAITB(0); COMPUTE(0);                       // kt = 63

    // ------------------------------------------------------------------ epi
    // All 4 gates wave-local.  C/D: col = lane&15, row = (lane>>4)*4 + reg
    const int lrc   = lane & 15;
    const int lquad = lane >> 4;
    const int colg  = bn0 + wcg * 16 + lrc;
    const int wrow  = wM * 64;
    float* out_ct = out;
    float* out_ht = out + (size_t)M_DIM * H_DIM;

    const float bf_ = bxf[colg] + bhf[colg];
    const float bi_ = bxi[colg] + bhi[colg];
    const float bo_ = bxo[colg] + bho[colg];
    const float bc_ = bxc[colg] + bhc[colg];

#pragma unroll
    for (int mt = 0; mt < 4; ++mt) {
#pragma unroll
        for (int r = 0; r < 4; ++r) {
            const int row = bm0 + wrow + mt * 16 + lquad * 4 + r;
            const float f    = fast_sigmoid(acc[0][mt][r] + bf_);
            const float ii   = fast_sigmoid(acc[1][mt][r] + bi_);
            const float o    = fast_sigmoid(acc[2][mt][r] + bo_);
            const float ctil = fast_tanh(acc[3][mt][r] + bc_);
            const float cv   = c[(size_t)row * H_DIM + colg];
            const float ctn  = f * cv + ctil * ii;
            const float htn  = fast_tanh(ctn) * o;
            out_ct[(size_t)row * H_DIM + colg] = ctn;
            out_ht[(size_t)row * H_DIM + colg] = htn;
        }
    }
}

extern "C" void kernel_launch(void* const* d_in, const int* in_sizes, int n_in,
                              void* d_out, int out_size, void* d_ws, size_t ws_size,
                              hipStream_t stream) {
    (void)in_sizes; (void)n_in; (void)out_size; (void)ws_size;
    const float* x   = (const float*)d_in[0];
    const float* c   = (const float*)d_in[1];
    const float* h   = (const float*)d_in[2];
    const float* Wxf = (const float*)d_in[3];  const float* bxf = (const float*)d_in[4];
    const float* Whf = (const float*)d_in[5];  const float* bhf = (const float*)d_in[6];
    const float* Wxi = (const float*)d_in[7];  const float* bxi = (const float*)d_in[8];
    const float* Whi = (const float*)d_in[9];  const float* bhi = (const float*)d_in[10];
    const float* Wxo = (const float*)d_in[11]; const float* bxo = (const float*)d_in[12];
    const float* Who = (const float*)d_in[13]; const float* bho = (const float*)d_in[14];
    const float* Wxc = (const float*)d_in[15]; const float* bxc = (const float*)d_in[16];
    const float* Whc = (const float*)d_in[17]; const float* bhc = (const float*)d_in[18];
    float* out = (float*)d_out;
    unsigned short* ws = (unsigned short*)d_ws;   // 32768 chunks x 1 KB = 32 MB

    pack_bf16<<<8192, 256, 0, stream>>>(x, h,
        Wxf, Wxi, Wxo, Wxc, Whf, Whi, Who, Whc, ws);

    lstm_fused_kernel<<<512, 512, 0, stream>>>(ws, c,
        bxf, bhf, bxi, bhi, bxo, bho, bxc, bhc, out);
}